// Round 5
// baseline (1062.468 us; speedup 1.0000x reference)
//
#include <hip/hip_runtime.h>
#include <hip/hip_cooperative_groups.h>
#include <stdint.h>

namespace cg = cooperative_groups;

#define BN 4096
#define DD 128
#define EPSF 1e-6f
#define MARGINF 1.0f

typedef unsigned long long ull;
typedef unsigned short ushort;
typedef short short8 __attribute__((ext_vector_type(8)));
typedef float f32x4 __attribute__((ext_vector_type(4)));

__device__ __forceinline__ unsigned int ord_f32(float f) {
    unsigned int u = __float_as_uint(f);
    return (u & 0x80000000u) ? ~u : (u | 0x80000000u);
}
__device__ __forceinline__ ushort bf16_rne(float x) {
    unsigned int u = __float_as_uint(x);
    return (ushort)((u + 0x7FFFu + ((u >> 16) & 1u)) >> 16);
}

struct Shm {
    ull scrp[64];
    ull scrn[64];
    float red[8];
};

// ---------------- Phase P: prep e (bf16 row + permuted copies), per-column
// tables, key init. bid in [0,1024).
__device__ __forceinline__ void phase_prep(int bid, int tid,
        const float* __restrict__ e, const int* __restrict__ tidx,
        float* __restrict__ rjp, unsigned int* __restrict__ jn,
        ull* __restrict__ pkey, ull* __restrict__ nkey,
        unsigned int* __restrict__ ehi, unsigned int* __restrict__ eperm) {
    const int w = tid >> 6, lane = tid & 63;
    const int row = bid * 4 + w;
    const int c = tidx[row];                 // wave-uniform broadcast
    float2 v = ((const float2*)(e + (size_t)row * DD))[lane];
    ushort hx = bf16_rne(v.x), hy = bf16_rne(v.y);
    unsigned int packed = (unsigned int)hx | ((unsigned int)hy << 16);
    ehi[row * 64 + lane] = packed;
    eperm[(size_t)c * 64 + lane] = packed;   // permuted-column copy
    float ss = v.x + v.y;
    float qq = v.x * v.x + v.y * v.y;
    #pragma unroll
    for (int off = 32; off > 0; off >>= 1) {
        ss += __shfl_down(ss, off);
        qq += __shfl_down(qq, off);
    }
    if (lane == 0) {
        rjp[c] = qq - 2.0f * EPSF * ss;
        jn[c] = 0xFFFFFFFFu - (unsigned int)row;
        pkey[row] = 0ULL; nkey[row] = 0ULL;
    }
}

// ---------------- Phase S: MFMA + selection; bid -> 16 rows x 1024 cols tile.
// Identical algorithm to round-3's proven k_select; rj/jn read from global
// (L2-hot) instead of LDS so block LDS stays ~1.2 KB (co-residency safe).
__device__ __forceinline__ void phase_select(int bid, int tid, Shm& shm,
        const ushort* __restrict__ ehi, const ushort* __restrict__ eperm,
        const int* __restrict__ pos, const int* __restrict__ neg,
        const float* __restrict__ rjp, const unsigned int* __restrict__ jn,
        ull* __restrict__ pkey, ull* __restrict__ nkey) {
    const int lane = tid & 63, w = tid >> 6;
    const int lrow = lane & 15, quad = lane >> 4;
    const int bx = bid & 255, by = bid >> 8;
    const int r0 = bx * 16, c0 = by * 1024;

    // A fragments: 16 rows, loaded once, reused for all 16 column tiles
    short8 a[4];
    #pragma unroll
    for (int ks = 0; ks < 4; ks++)
        a[ks] = *(const short8*)(ehi + (size_t)(r0 + lrow) * DD + ks * 32 + quad * 8);

    ull kp[4] = {0ULL, 0ULL, 0ULL, 0ULL};
    ull kn[4] = {0ULL, 0ULL, 0ULL, 0ULL};

    int pm[2][4], nm[2][4];
    short8 bf[2][4];
    float rjc[2]; unsigned int jni[2];

#define LOADTILE(BUF, JT) do {                                                 \
        const int lcol = (JT) * 64 + w * 16 + lrow;                            \
        rjc[BUF] = rjp[c0 + lcol];                                             \
        jni[BUF] = jn[c0 + lcol];                                              \
        const int* pp = pos + (size_t)(r0 + quad * 4) * BN + (size_t)(c0 + lcol); \
        const int* np = neg + (size_t)(r0 + quad * 4) * BN + (size_t)(c0 + lcol); \
        _Pragma("unroll")                                                      \
        for (int t = 0; t < 4; t++) {                                          \
            pm[BUF][t] = __builtin_nontemporal_load(pp + (size_t)t * BN);      \
            nm[BUF][t] = __builtin_nontemporal_load(np + (size_t)t * BN);      \
        }                                                                      \
        const ushort* bp = eperm + (size_t)(c0 + lcol) * DD + quad * 8;        \
        _Pragma("unroll")                                                      \
        for (int ks = 0; ks < 4; ks++)                                         \
            bf[BUF][ks] = *(const short8*)(bp + ks * 32);                      \
    } while (0)

    LOADTILE(0, 0);

    #pragma unroll
    for (int jt = 0; jt < 16; jt++) {
        const int cur = jt & 1, nxt = cur ^ 1;
        if (jt < 15) {
            if (nxt == 0) LOADTILE(0, jt + 1); else LOADTILE(1, jt + 1);
        }
        f32x4 acc = (f32x4){0.f, 0.f, 0.f, 0.f};
        #pragma unroll
        for (int ks = 0; ks < 4; ks++)
            acc = __builtin_amdgcn_mfma_f32_16x16x32_bf16(a[ks], bf[cur][ks], acc, 0, 0, 0);
        // selection on m = rj - 2*dot (row-constant terms dropped)
        #pragma unroll
        for (int t = 0; t < 4; t++) {
            float m = rjc[cur] - 2.0f * acc[t];
            unsigned int om = ord_f32(m);
            ull keyp = ((ull)om << 32) | (ull)jni[cur];
            ull keyn = ((ull)(om ^ 0xFFFFFFFFu) << 32) | (ull)jni[cur];
            if (pm[cur][t] != 0 && keyp > kp[t]) kp[t] = keyp;   // max-m, ties -> smaller j
            if (nm[cur][t] != 0 && keyn > kn[t]) kn[t] = keyn;   // min-m, ties -> smaller j
        }
    }
#undef LOADTILE

    // fold across the 16 lanes of each quad (same rows, different cols)
    #pragma unroll
    for (int t = 0; t < 4; t++) {
        #pragma unroll
        for (int off = 8; off > 0; off >>= 1) {
            ull o = __shfl_xor(kp[t], off); if (o > kp[t]) kp[t] = o;
            o = __shfl_xor(kn[t], off);     if (o > kn[t]) kn[t] = o;
        }
        if (lrow == 0) {
            shm.scrp[(quad * 4 + t) * 4 + w] = kp[t];
            shm.scrn[(quad * 4 + t) * 4 + w] = kn[t];
        }
    }
    __syncthreads();
    if (tid < 16) {
        ull xp = 0ULL, xn = 0ULL;
        #pragma unroll
        for (int k = 0; k < 4; k++) {
            ull v = shm.scrp[tid * 4 + k]; if (v > xp) xp = v;
            v = shm.scrn[tid * 4 + k];     if (v > xn) xn = v;
        }
        if (xp) atomicMax(&pkey[r0 + tid], xp);
        if (xn) atomicMax(&nkey[r0 + tid], xn);
    }
}

// ---------------- Phase L: per-row triplet loss, block partials
__device__ __forceinline__ void phase_loss(int bid, int tid, Shm& shm,
        const float* __restrict__ e,
        const ull* __restrict__ pkey, const ull* __restrict__ nkey,
        float* __restrict__ partials) {
    const int w = tid >> 6, lane = tid & 63;
    const int row = bid * 4 + w;
    ull pk = pkey[row], nk = nkey[row];
    float loss = 0.0f, wt = 0.0f;
    if (pk != 0ULL && nk != 0ULL) {
        int pi = (int)(0xFFFFFFFFu - (unsigned)(pk & 0xFFFFFFFFu));
        int ni = (int)(0xFFFFFFFFu - (unsigned)(nk & 0xFFFFFFFFu));
        float2 av = ((const float2*)(e + (size_t)row * DD))[lane];
        float2 pv = ((const float2*)(e + (size_t)pi * DD))[lane];
        float2 nv = ((const float2*)(e + (size_t)ni * DD))[lane];
        float dx, dy;
        dx = av.x - pv.x + EPSF; dy = av.y - pv.y + EPSF;
        float ap2 = dx * dx + dy * dy;
        dx = av.x - nv.x + EPSF; dy = av.y - nv.y + EPSF;
        float an2 = dx * dx + dy * dy;
        dx = pv.x - nv.x + EPSF; dy = pv.y - nv.y + EPSF;
        float pn2 = dx * dx + dy * dy;
        #pragma unroll
        for (int off = 32; off > 0; off >>= 1) {
            ap2 += __shfl_down(ap2, off);
            an2 += __shfl_down(an2, off);
            pn2 += __shfl_down(pn2, off);
        }
        if (lane == 0) {
            float ap = sqrtf(ap2), an = sqrtf(an2), pn = sqrtf(pn2);
            loss = fmaxf(ap - fminf(an, pn) + MARGINF, 0.0f);
            wt = 1.0f;
        }
    }
    if (lane == 0) { shm.red[w] = loss; shm.red[4 + w] = wt; }
    __syncthreads();
    if (tid == 0) {
        partials[bid * 2 + 0] = shm.red[0] + shm.red[1] + shm.red[2] + shm.red[3];
        partials[bid * 2 + 1] = shm.red[4] + shm.red[5] + shm.red[6] + shm.red[7];
    }
}

// ---------------- Phase F: final reduce (single block, fixed order)
__device__ __forceinline__ void phase_final(int tid, Shm& shm,
        const float* __restrict__ partials, float* __restrict__ out) {
    float L = 0.0f, W = 0.0f;
    #pragma unroll
    for (int i = 0; i < 4; i++) {
        int idx = tid + i * 256;
        L += partials[idx * 2];
        W += partials[idx * 2 + 1];
    }
    #pragma unroll
    for (int off = 32; off > 0; off >>= 1) {
        L += __shfl_down(L, off);
        W += __shfl_down(W, off);
    }
    const int w = tid >> 6, lane = tid & 63;
    if (lane == 0) { shm.red[w] = L; shm.red[4 + w] = W; }
    __syncthreads();
    if (tid == 0) {
        float Lt = shm.red[0] + shm.red[1] + shm.red[2] + shm.red[3];
        float Wt = shm.red[4] + shm.red[5] + shm.red[6] + shm.red[7];
        out[0] = Lt / fmaxf(Wt, 1.0f);
    }
}

// ---------------- fused cooperative kernel ----------------
__global__ __launch_bounds__(256, 4)
void k_all(const float* __restrict__ e, const int* __restrict__ tidx,
           const int* __restrict__ pos, const int* __restrict__ neg,
           float* __restrict__ rjp, unsigned int* __restrict__ jn,
           ull* __restrict__ pkey, ull* __restrict__ nkey,
           unsigned int* __restrict__ ehi, unsigned int* __restrict__ eperm,
           float* __restrict__ partials, float* __restrict__ out) {
    cg::grid_group grid = cg::this_grid();
    __shared__ Shm shm;
    const int tid = threadIdx.x;
    const int bid = blockIdx.x;

    phase_prep(bid, tid, e, tidx, rjp, jn, pkey, nkey, ehi, eperm);
    __threadfence(); grid.sync(); __threadfence();   // release + ACQUIRE (stale-L2 kill)

    phase_select(bid, tid, shm, (const ushort*)ehi, (const ushort*)eperm,
                 pos, neg, rjp, jn, pkey, nkey);
    __threadfence(); grid.sync(); __threadfence();

    phase_loss(bid, tid, shm, e, pkey, nkey, partials);
    __threadfence(); grid.sync(); __threadfence();

    if (bid == 0) phase_final(tid, shm, partials, out);
}

// ---------------- split fallback kernels (identical phase code) ----------------
__global__ void k_prep_k(const float* __restrict__ e, const int* __restrict__ tidx,
                         float* __restrict__ rjp, unsigned int* __restrict__ jn,
                         ull* __restrict__ pkey, ull* __restrict__ nkey,
                         unsigned int* __restrict__ ehi, unsigned int* __restrict__ eperm) {
    phase_prep(blockIdx.x, threadIdx.x, e, tidx, rjp, jn, pkey, nkey, ehi, eperm);
}
__global__ __launch_bounds__(256, 4)
void k_select_k(const ushort* __restrict__ ehi, const ushort* __restrict__ eperm,
                const int* __restrict__ pos, const int* __restrict__ neg,
                const float* __restrict__ rjp, const unsigned int* __restrict__ jn,
                ull* __restrict__ pkey, ull* __restrict__ nkey) {
    __shared__ Shm shm;
    phase_select(blockIdx.x, threadIdx.x, shm, ehi, eperm, pos, neg, rjp, jn, pkey, nkey);
}
__global__ void k_loss_k(const float* __restrict__ e,
                         const ull* __restrict__ pkey, const ull* __restrict__ nkey,
                         float* __restrict__ partials) {
    __shared__ Shm shm;
    phase_loss(blockIdx.x, threadIdx.x, shm, e, pkey, nkey, partials);
}
__global__ void k_final_k(const float* __restrict__ partials, float* __restrict__ out) {
    __shared__ Shm shm;
    phase_final(threadIdx.x, shm, partials, out);
}

extern "C" void kernel_launch(void* const* d_in, const int* in_sizes, int n_in,
                              void* d_out, int out_size, void* d_ws, size_t ws_size,
                              hipStream_t stream) {
    const float* e    = (const float*)d_in[0];
    const int*   tidx = (const int*)d_in[1];
    const int*   pos  = (const int*)d_in[2];
    const int*   neg  = (const int*)d_in[3];
    float* out = (float*)d_out;

    // workspace layout identical to round 3 (proven): ~2.2 MB
    ull* pkey  = (ull*)d_ws;                          // 4096 ull
    ull* nkey  = pkey + BN;                           // 4096 ull
    float* rjp = (float*)(nkey + BN);                 // 4096 f32
    unsigned int* jn = (unsigned int*)(rjp + BN);     // 4096 u32
    float* partials  = (float*)(jn + BN);             // 2048 f32
    unsigned int* ehi   = (unsigned int*)(partials + 2048);   // 4096*64 u32 (1 MB)
    unsigned int* eperm = ehi + (size_t)BN * 64;              // 4096*64 u32 (1 MB)

    void* args[] = {
        (void*)&e, (void*)&tidx, (void*)&pos, (void*)&neg,
        (void*)&rjp, (void*)&jn, (void*)&pkey, (void*)&nkey,
        (void*)&ehi, (void*)&eperm, (void*)&partials, (void*)&out
    };
    hipError_t rc = hipLaunchCooperativeKernel((const void*)k_all, dim3(1024), dim3(256),
                                               args, 0, stream);
    if (rc != hipSuccess) {
        // validation failed (e.g. co-residency) -> proven 4-kernel chain
        k_prep_k<<<1024, 256, 0, stream>>>(e, tidx, rjp, jn, pkey, nkey, ehi, eperm);
        k_select_k<<<1024, 256, 0, stream>>>((const ushort*)ehi, (const ushort*)eperm,
                                             pos, neg, rjp, jn, pkey, nkey);
        k_loss_k<<<1024, 256, 0, stream>>>(e, pkey, nkey, partials);
        k_final_k<<<1, 256, 0, stream>>>(partials, out);
    }
}

// Round 6
// 213.695 us; speedup vs baseline: 4.9719x; 4.9719x over previous
//
#include <hip/hip_runtime.h>
#include <stdint.h>

#define BN 4096
#define DD 128
#define EPSF 1e-6f
#define MARGINF 1.0f

typedef unsigned long long ull;
typedef unsigned short ushort;
typedef short short8 __attribute__((ext_vector_type(8)));
typedef float f32x4 __attribute__((ext_vector_type(4)));
typedef int int4v __attribute__((ext_vector_type(4)));

__device__ __forceinline__ unsigned int ord_f32(float f) {
    unsigned int u = __float_as_uint(f);
    return (u & 0x80000000u) ? ~u : (u | 0x80000000u);
}
__device__ __forceinline__ ushort bf16_rne(float x) {
    unsigned int u = __float_as_uint(x);
    return (ushort)((u + 0x7FFFu + ((u >> 16) & 1u)) >> 16);
}

// --- prep: bf16 convert (row + permuted copies), per-column tables, key init,
//     and (BITS) mask bit-compress via PURE SEQUENTIAL streaming reads.
//     Compress moves the 128 MB mask stream out of k_select's mixed-access
//     pattern (measured ~1.4 TB/s there) into the DRAM-optimal shape, and
//     shrinks what k_select reads to 4 MB of L2-hot bit words.
template<bool BITS>
__global__ void k_prep(const float* __restrict__ e, const int* __restrict__ tidx,
                       const int* __restrict__ pos, const int* __restrict__ neg,
                       float* __restrict__ rjp, unsigned int* __restrict__ jn,
                       ull* __restrict__ pkey, ull* __restrict__ nkey,
                       unsigned int* __restrict__ ehi, unsigned int* __restrict__ eperm,
                       ull* __restrict__ pbits, ull* __restrict__ nbits) {
    const int w = threadIdx.x >> 6, lane = threadIdx.x & 63;
    const int row = blockIdx.x * 4 + w;
    const int c = tidx[row];                 // wave-uniform broadcast
    float2 v = ((const float2*)(e + (size_t)row * DD))[lane];
    ushort hx = bf16_rne(v.x), hy = bf16_rne(v.y);
    unsigned int packed = (unsigned int)hx | ((unsigned int)hy << 16);
    ehi[row * 64 + lane] = packed;
    eperm[(size_t)c * 64 + lane] = packed;   // permuted-column copy
    float ss = v.x + v.y;
    float qq = v.x * v.x + v.y * v.y;
    #pragma unroll
    for (int off = 32; off > 0; off >>= 1) {
        ss += __shfl_down(ss, off);
        qq += __shfl_down(qq, off);
    }
    if (lane == 0) {
        rjp[c] = qq - 2.0f * EPSF * ss;
        jn[c] = 0xFFFFFFFFu - (unsigned int)row;
        pkey[row] = 0ULL; nkey[row] = 0ULL;
    }
    if (BITS) {
        // bit-compress this row's masks: lane covers cols seg*1024+lane*16..+15
        // (ushort word index = col/16; ull view: bit q of ull m <-> col 64m+q)
        ushort* pb16 = (ushort*)pbits;
        ushort* nb16 = (ushort*)nbits;
        const int4v* prow = (const int4v*)(pos + (size_t)row * BN);
        const int4v* nrow = (const int4v*)(neg + (size_t)row * BN);
        #pragma unroll
        for (int seg = 0; seg < 4; seg++) {
            unsigned int pu = 0, nu = 0;
            #pragma unroll
            for (int k = 0; k < 4; k++) {
                int4v P = __builtin_nontemporal_load(&prow[seg * 256 + lane * 4 + k]);
                int4v N = __builtin_nontemporal_load(&nrow[seg * 256 + lane * 4 + k]);
                unsigned int pq = (unsigned int)(P[0] != 0) | ((unsigned int)(P[1] != 0) << 1)
                                | ((unsigned int)(P[2] != 0) << 2) | ((unsigned int)(P[3] != 0) << 3);
                unsigned int nq = (unsigned int)(N[0] != 0) | ((unsigned int)(N[1] != 0) << 1)
                                | ((unsigned int)(N[2] != 0) << 2) | ((unsigned int)(N[3] != 0) << 3);
                pu |= pq << (4 * k);
                nu |= nq << (4 * k);
            }
            pb16[row * 256 + seg * 64 + lane] = (ushort)pu;   // 128 B contiguous/wave
            nb16[row * 256 + seg * 64 + lane] = (ushort)nu;
        }
    }
}

// --- fused MFMA + selection; block = 16 rows x 1024 cols ---
// BITS=1: masks come as 8 broadcast ull words/tile from the 4 MB bit array
// (L2-hot). BITS=0: round-3 proven raw nontemporal dword loads (fallback).
template<bool BITS>
__global__ __launch_bounds__(256, 4)
void k_select(const ushort* __restrict__ ehi, const ushort* __restrict__ eperm,
              const int* __restrict__ pos, const int* __restrict__ neg,
              const ull* __restrict__ pbits, const ull* __restrict__ nbits,
              const float* __restrict__ rjp, const unsigned int* __restrict__ jn,
              ull* __restrict__ pkey, ull* __restrict__ nkey) {
    __shared__ float rjL[1024];
    __shared__ unsigned int jnL[1024];
    __shared__ ull scrp[64], scrn[64];

    const int tid = threadIdx.x;
    const int lane = tid & 63, w = tid >> 6;
    const int lrow = lane & 15, quad = lane >> 4;
    const int r0 = blockIdx.x * 16;
    const int c0 = blockIdx.y * 1024;
    const int cb0 = c0 >> 6;
    const int shft = w * 16 + lrow;          // bit position within a 64-col word

    #pragma unroll
    for (int k = 0; k < 4; k++) {
        int idx = k * 256 + tid;
        rjL[idx] = rjp[c0 + idx];
        jnL[idx] = jn[c0 + idx];
    }

    // A fragments: 16 rows, loaded ONCE, reused for all 16 column tiles
    short8 a[4];
    #pragma unroll
    for (int ks = 0; ks < 4; ks++)
        a[ks] = *(const short8*)(ehi + (size_t)(r0 + lrow) * DD + ks * 32 + quad * 8);

    __syncthreads();

    ull kp[4] = {0ULL, 0ULL, 0ULL, 0ULL};
    ull kn[4] = {0ULL, 0ULL, 0ULL, 0ULL};

    ull pmw[2][4], nmw[2][4];                // BITS=1 path
    int pm[2][4], nm[2][4];                  // BITS=0 path
    short8 bf[2][4];
    float rjc[2]; unsigned int jni[2];

#define LOADTILE(BUF, JT) do {                                                  \
        const int lcol = (JT) * 64 + shft;                                      \
        rjc[BUF] = rjL[lcol];                                                   \
        jni[BUF] = jnL[lcol];                                                   \
        if (BITS) {                                                             \
            const ull* pb = pbits + (size_t)(r0 + quad * 4) * 64 + cb0 + (JT);  \
            const ull* nb = nbits + (size_t)(r0 + quad * 4) * 64 + cb0 + (JT);  \
            _Pragma("unroll")                                                   \
            for (int t = 0; t < 4; t++) {                                       \
                pmw[BUF][t] = pb[(size_t)t * 64];                               \
                nmw[BUF][t] = nb[(size_t)t * 64];                               \
            }                                                                   \
        } else {                                                                \
            const int* pp = pos + (size_t)(r0 + quad * 4) * BN + (size_t)(c0 + lcol); \
            const int* np = neg + (size_t)(r0 + quad * 4) * BN + (size_t)(c0 + lcol); \
            _Pragma("unroll")                                                   \
            for (int t = 0; t < 4; t++) {                                       \
                pm[BUF][t] = __builtin_nontemporal_load(pp + (size_t)t * BN);   \
                nm[BUF][t] = __builtin_nontemporal_load(np + (size_t)t * BN);   \
            }                                                                   \
        }                                                                       \
        const ushort* bp = eperm + (size_t)(c0 + lcol) * DD + quad * 8;         \
        _Pragma("unroll")                                                       \
        for (int ks = 0; ks < 4; ks++)                                          \
            bf[BUF][ks] = *(const short8*)(bp + ks * 32);                       \
    } while (0)

    LOADTILE(0, 0);

    #pragma unroll
    for (int jt = 0; jt < 16; jt++) {
        const int cur = jt & 1, nxt = cur ^ 1;
        if (jt < 15) {
            if (nxt == 0) LOADTILE(0, jt + 1); else LOADTILE(1, jt + 1);
        }
        f32x4 acc = (f32x4){0.f, 0.f, 0.f, 0.f};
        #pragma unroll
        for (int ks = 0; ks < 4; ks++)
            acc = __builtin_amdgcn_mfma_f32_16x16x32_bf16(a[ks], bf[cur][ks], acc, 0, 0, 0);
        // selection on m = rj - 2*dot (row-constant terms dropped)
        #pragma unroll
        for (int t = 0; t < 4; t++) {
            float m = rjc[cur] - 2.0f * acc[t];
            unsigned int om = ord_f32(m);
            ull keyp = ((ull)om << 32) | (ull)jni[cur];
            ull keyn = ((ull)(om ^ 0xFFFFFFFFu) << 32) | (ull)jni[cur];
            bool pok = BITS ? (((pmw[cur][t] >> shft) & 1ULL) != 0ULL) : (pm[cur][t] != 0);
            bool nok = BITS ? (((nmw[cur][t] >> shft) & 1ULL) != 0ULL) : (nm[cur][t] != 0);
            if (pok && keyp > kp[t]) kp[t] = keyp;   // max-m, ties -> smaller j
            if (nok && keyn > kn[t]) kn[t] = keyn;   // min-m, ties -> smaller j
        }
    }
#undef LOADTILE

    // fold across the 16 lanes of each quad (same rows, different cols)
    #pragma unroll
    for (int t = 0; t < 4; t++) {
        #pragma unroll
        for (int off = 8; off > 0; off >>= 1) {
            ull o = __shfl_xor(kp[t], off); if (o > kp[t]) kp[t] = o;
            o = __shfl_xor(kn[t], off);     if (o > kn[t]) kn[t] = o;
        }
        if (lrow == 0) {
            scrp[(quad * 4 + t) * 4 + w] = kp[t];
            scrn[(quad * 4 + t) * 4 + w] = kn[t];
        }
    }
    __syncthreads();
    if (tid < 16) {
        ull xp = 0ULL, xn = 0ULL;
        #pragma unroll
        for (int k = 0; k < 4; k++) {
            ull v = scrp[tid * 4 + k]; if (v > xp) xp = v;
            v = scrn[tid * 4 + k];     if (v > xn) xn = v;
        }
        if (xp) atomicMax(&pkey[r0 + tid], xp);
        if (xn) atomicMax(&nkey[r0 + tid], xn);
    }
}

// --- per-row triplet loss: wave per row (coalesced), block partials ---
__global__ void k_loss(const float* __restrict__ e,
                       const ull* __restrict__ pkey, const ull* __restrict__ nkey,
                       float* __restrict__ partials) {
    int w = threadIdx.x >> 6, lane = threadIdx.x & 63;
    int row = blockIdx.x * 4 + w;
    ull pk = pkey[row], nk = nkey[row];
    float loss = 0.0f, wt = 0.0f;
    if (pk != 0ULL && nk != 0ULL) {
        int pi = (int)(0xFFFFFFFFu - (unsigned)(pk & 0xFFFFFFFFu));
        int ni = (int)(0xFFFFFFFFu - (unsigned)(nk & 0xFFFFFFFFu));
        float2 av = ((const float2*)(e + (size_t)row * DD))[lane];
        float2 pv = ((const float2*)(e + (size_t)pi * DD))[lane];
        float2 nv = ((const float2*)(e + (size_t)ni * DD))[lane];
        float dx, dy;
        dx = av.x - pv.x + EPSF; dy = av.y - pv.y + EPSF;
        float ap2 = dx * dx + dy * dy;
        dx = av.x - nv.x + EPSF; dy = av.y - nv.y + EPSF;
        float an2 = dx * dx + dy * dy;
        dx = pv.x - nv.x + EPSF; dy = pv.y - nv.y + EPSF;
        float pn2 = dx * dx + dy * dy;
        #pragma unroll
        for (int off = 32; off > 0; off >>= 1) {
            ap2 += __shfl_down(ap2, off);
            an2 += __shfl_down(an2, off);
            pn2 += __shfl_down(pn2, off);
        }
        if (lane == 0) {
            float ap = sqrtf(ap2), an = sqrtf(an2), pn = sqrtf(pn2);
            loss = fmaxf(ap - fminf(an, pn) + MARGINF, 0.0f);
            wt = 1.0f;
        }
    }
    __shared__ float sl[4], sw[4];
    if (lane == 0) { sl[w] = loss; sw[w] = wt; }
    __syncthreads();
    if (threadIdx.x == 0) {
        partials[blockIdx.x * 2 + 0] = sl[0] + sl[1] + sl[2] + sl[3];
        partials[blockIdx.x * 2 + 1] = sw[0] + sw[1] + sw[2] + sw[3];
    }
}

// --- finalize ---
__global__ void k_final(const float* __restrict__ partials, float* __restrict__ out) {
    int tid = threadIdx.x;
    float L = 0.0f, W = 0.0f;
    for (int i = 0; i < 4; i++) {
        int idx = tid + i * 256;
        L += partials[idx * 2];
        W += partials[idx * 2 + 1];
    }
    #pragma unroll
    for (int off = 32; off > 0; off >>= 1) {
        L += __shfl_down(L, off);
        W += __shfl_down(W, off);
    }
    __shared__ float sl[4], sw[4];
    int w = tid >> 6, lane = tid & 63;
    if (lane == 0) { sl[w] = L; sw[w] = W; }
    __syncthreads();
    if (tid == 0) {
        float Lt = sl[0] + sl[1] + sl[2] + sl[3];
        float Wt = sw[0] + sw[1] + sw[2] + sw[3];
        out[0] = Lt / fmaxf(Wt, 1.0f);
    }
}

extern "C" void kernel_launch(void* const* d_in, const int* in_sizes, int n_in,
                              void* d_out, int out_size, void* d_ws, size_t ws_size,
                              hipStream_t stream) {
    const float* e    = (const float*)d_in[0];
    const int*   tidx = (const int*)d_in[1];
    const int*   pos  = (const int*)d_in[2];
    const int*   neg  = (const int*)d_in[3];
    float* out = (float*)d_out;

    char* p = (char*)d_ws;
    ull* pkey  = (ull*)p;                 p += (size_t)BN * 8;     // 32 KB
    ull* nkey  = (ull*)p;                 p += (size_t)BN * 8;     // 32 KB
    float* rjp = (float*)p;               p += (size_t)BN * 4;     // 16 KB
    unsigned int* jn = (unsigned int*)p;  p += (size_t)BN * 4;     // 16 KB
    float* partials = (float*)p;          p += 2048 * 4;           // 8 KB
    unsigned int* ehi = (unsigned int*)p; p += (size_t)BN * 64 * 4; // 1 MB
    unsigned int* eperm = (unsigned int*)p; p += (size_t)BN * 64 * 4; // 1 MB
    ull* pbits = (ull*)p;                 p += (size_t)BN * 64 * 8; // 2 MB
    ull* nbits = (ull*)p;                 p += (size_t)BN * 64 * 8; // 2 MB
    const size_t need = (size_t)(p - (char*)d_ws);
    const bool bits = ws_size >= need;    // fallback to proven raw path if ws too small

    dim3 grid(BN / 16, 4);
    if (bits) {
        k_prep<true><<<BN / 4, 256, 0, stream>>>(e, tidx, pos, neg, rjp, jn,
                                                 pkey, nkey, ehi, eperm, pbits, nbits);
        k_select<true><<<grid, 256, 0, stream>>>((const ushort*)ehi, (const ushort*)eperm,
                                                 pos, neg, pbits, nbits,
                                                 rjp, jn, pkey, nkey);
    } else {
        k_prep<false><<<BN / 4, 256, 0, stream>>>(e, tidx, pos, neg, rjp, jn,
                                                  pkey, nkey, ehi, eperm, pbits, nbits);
        k_select<false><<<grid, 256, 0, stream>>>((const ushort*)ehi, (const ushort*)eperm,
                                                  pos, neg, pbits, nbits,
                                                  rjp, jn, pkey, nkey);
    }
    k_loss<<<BN / 4, 256, 0, stream>>>(e, pkey, nkey, partials);
    k_final<<<1, 256, 0, stream>>>(partials, out);
}

// Round 7
// 186.485 us; speedup vs baseline: 5.6974x; 1.1459x over previous
//
#include <hip/hip_runtime.h>
#include <stdint.h>

#define BN 4096
#define DD 128
#define EPSF 1e-6f
#define MARGINF 1.0f

typedef unsigned long long ull;
typedef unsigned short ushort;
typedef short short8 __attribute__((ext_vector_type(8)));
typedef float f32x4 __attribute__((ext_vector_type(4)));

__device__ __forceinline__ unsigned int ord_f32(float f) {
    unsigned int u = __float_as_uint(f);
    return (u & 0x80000000u) ? ~u : (u | 0x80000000u);
}
__device__ __forceinline__ ushort bf16_rne(float x) {
    unsigned int u = __float_as_uint(x);
    return (ushort)((u + 0x7FFFu + ((u >> 16) & 1u)) >> 16);
}

// --- prep + mask bit-compress (ballot path) ---
// One wave per row. Mask loads are dword-per-lane, perfectly coalesced,
// 1 VGPR per outstanding load -> 32 loads (8 KB/wave) in flight (the R6
// int4 version was VGPR-starved at ~2 loads in flight, 2.3 TB/s).
// __ballot(v!=0) IS the 64-col bit word; park word j in lane j, then one
// coalesced 8 B/lane store per mask per row.
__global__ __launch_bounds__(256)
void k_prep(const float* __restrict__ e, const int* __restrict__ tidx,
            const int* __restrict__ pos, const int* __restrict__ neg,
            float* __restrict__ rjp, unsigned int* __restrict__ jn,
            ull* __restrict__ pkey, ull* __restrict__ nkey,
            unsigned int* __restrict__ ehi, unsigned int* __restrict__ eperm,
            ull* __restrict__ pbits, ull* __restrict__ nbits) {
    const int w = threadIdx.x >> 6, lane = threadIdx.x & 63;
    const int row = blockIdx.x * 4 + w;
    const int c = tidx[row];                 // wave-uniform broadcast
    float2 v = ((const float2*)(e + (size_t)row * DD))[lane];
    ushort hx = bf16_rne(v.x), hy = bf16_rne(v.y);
    unsigned int packed = (unsigned int)hx | ((unsigned int)hy << 16);
    ehi[row * 64 + lane] = packed;
    eperm[(size_t)c * 64 + lane] = packed;   // permuted-column copy
    float ss = v.x + v.y;
    float qq = v.x * v.x + v.y * v.y;
    #pragma unroll
    for (int off = 32; off > 0; off >>= 1) {
        ss += __shfl_down(ss, off);
        qq += __shfl_down(qq, off);
    }
    if (lane == 0) {
        rjp[c] = qq - 2.0f * EPSF * ss;
        jn[c] = 0xFFFFFFFFu - (unsigned int)row;
        pkey[row] = 0ULL; nkey[row] = 0ULL;
    }

    // bit-compress this wave's row: word m covers cols 64m..64m+63; bit l = col 64m+l
    const int* prow = pos + (size_t)row * BN;
    const int* nrow = neg + (size_t)row * BN;
    ull myp = 0ULL, myn = 0ULL;
    #pragma unroll
    for (int j0 = 0; j0 < 64; j0 += 16) {
        int pv[16], nv[16];
        #pragma unroll
        for (int k = 0; k < 16; k++)
            pv[k] = __builtin_nontemporal_load(prow + (j0 + k) * 64 + lane);
        #pragma unroll
        for (int k = 0; k < 16; k++)
            nv[k] = __builtin_nontemporal_load(nrow + (j0 + k) * 64 + lane);
        #pragma unroll
        for (int k = 0; k < 16; k++) {
            ull bp = __ballot(pv[k] != 0);
            ull bn = __ballot(nv[k] != 0);
            if (lane == j0 + k) { myp = bp; myn = bn; }
        }
    }
    pbits[(size_t)row * 64 + lane] = myp;    // coalesced 512 B/wave
    nbits[(size_t)row * 64 + lane] = myn;
}

// --- fused MFMA + selection; block = 16 rows x 1024 cols ---
// The block's ENTIRE mask bit-tile is 4 KB -> staged to LDS once; in-loop
// mask reads are ds_read_b64 (no L2 round trips). Only remaining global
// stream in the loop: 4 B-fragment loads/iter from L2-hot eperm (2-deep
// prefetch). Select was measured ~45 us with all-L2 data => latency on the
// per-iteration scattered loads, which this removes.
__global__ __launch_bounds__(256, 4)
void k_select(const ushort* __restrict__ ehi, const ushort* __restrict__ eperm,
              const ull* __restrict__ pbits, const ull* __restrict__ nbits,
              const float* __restrict__ rjp, const unsigned int* __restrict__ jn,
              ull* __restrict__ pkey, ull* __restrict__ nkey) {
    __shared__ float rjL[1024];
    __shared__ unsigned int jnL[1024];
    __shared__ ull bitP[256], bitN[256];     // [16 rows][16 words]
    __shared__ ull scrp[64], scrn[64];

    const int tid = threadIdx.x;
    const int lane = tid & 63, w = tid >> 6;
    const int lrow = lane & 15, quad = lane >> 4;
    const int r0 = blockIdx.x * 16;
    const int c0 = blockIdx.y * 1024;
    const int cb0 = c0 >> 6;
    const int shft = w * 16 + lrow;          // bit position within a 64-col word

    #pragma unroll
    for (int k = 0; k < 4; k++) {
        int idx = k * 256 + tid;
        rjL[idx] = rjp[c0 + idx];
        jnL[idx] = jn[c0 + idx];
    }
    // stage the 4 KB bit tile: thread tid -> (local row tid>>4, word tid&15)
    bitP[tid] = pbits[(size_t)(r0 + (tid >> 4)) * 64 + cb0 + (tid & 15)];
    bitN[tid] = nbits[(size_t)(r0 + (tid >> 4)) * 64 + cb0 + (tid & 15)];

    // A fragments: 16 rows, loaded ONCE, reused for all 16 column tiles
    short8 a[4];
    #pragma unroll
    for (int ks = 0; ks < 4; ks++)
        a[ks] = *(const short8*)(ehi + (size_t)(r0 + lrow) * DD + ks * 32 + quad * 8);

    __syncthreads();

    ull kp[4] = {0ULL, 0ULL, 0ULL, 0ULL};
    ull kn[4] = {0ULL, 0ULL, 0ULL, 0ULL};

    short8 bf[2][4];
    float rjc[2]; unsigned int jni[2];

#define LOADTILE(BUF, JT) do {                                                  \
        const int lcol = (JT) * 64 + shft;                                      \
        rjc[BUF] = rjL[lcol];                                                   \
        jni[BUF] = jnL[lcol];                                                   \
        const ushort* bp = eperm + (size_t)(c0 + lcol) * DD + quad * 8;         \
        _Pragma("unroll")                                                       \
        for (int ks = 0; ks < 4; ks++)                                          \
            bf[BUF][ks] = *(const short8*)(bp + ks * 32);                       \
    } while (0)

    LOADTILE(0, 0);

    #pragma unroll
    for (int jt = 0; jt < 16; jt++) {
        const int cur = jt & 1, nxt = cur ^ 1;
        if (jt < 15) {
            if (nxt == 0) LOADTILE(0, jt + 1); else LOADTILE(1, jt + 1);
        }
        f32x4 acc = (f32x4){0.f, 0.f, 0.f, 0.f};
        #pragma unroll
        for (int ks = 0; ks < 4; ks++)
            acc = __builtin_amdgcn_mfma_f32_16x16x32_bf16(a[ks], bf[cur][ks], acc, 0, 0, 0);
        // selection on m = rj - 2*dot (row-constant terms dropped)
        #pragma unroll
        for (int t = 0; t < 4; t++) {
            ull pw = bitP[(quad * 4 + t) * 16 + jt];   // LDS broadcast per quad
            ull nw = bitN[(quad * 4 + t) * 16 + jt];
            float m = rjc[cur] - 2.0f * acc[t];
            unsigned int om = ord_f32(m);
            ull keyp = ((ull)om << 32) | (ull)jni[cur];
            ull keyn = ((ull)(om ^ 0xFFFFFFFFu) << 32) | (ull)jni[cur];
            if (((pw >> shft) & 1ULL) && keyp > kp[t]) kp[t] = keyp;   // max-m, ties -> smaller j
            if (((nw >> shft) & 1ULL) && keyn > kn[t]) kn[t] = keyn;   // min-m, ties -> smaller j
        }
    }
#undef LOADTILE

    // fold across the 16 lanes of each quad (same rows, different cols)
    #pragma unroll
    for (int t = 0; t < 4; t++) {
        #pragma unroll
        for (int off = 8; off > 0; off >>= 1) {
            ull o = __shfl_xor(kp[t], off); if (o > kp[t]) kp[t] = o;
            o = __shfl_xor(kn[t], off);     if (o > kn[t]) kn[t] = o;
        }
        if (lrow == 0) {
            scrp[(quad * 4 + t) * 4 + w] = kp[t];
            scrn[(quad * 4 + t) * 4 + w] = kn[t];
        }
    }
    __syncthreads();
    if (tid < 16) {
        ull xp = 0ULL, xn = 0ULL;
        #pragma unroll
        for (int k = 0; k < 4; k++) {
            ull v = scrp[tid * 4 + k]; if (v > xp) xp = v;
            v = scrn[tid * 4 + k];     if (v > xn) xn = v;
        }
        if (xp) atomicMax(&pkey[r0 + tid], xp);
        if (xn) atomicMax(&nkey[r0 + tid], xn);
    }
}

// --- per-row triplet loss: wave per row (coalesced), block partials ---
__global__ void k_loss(const float* __restrict__ e,
                       const ull* __restrict__ pkey, const ull* __restrict__ nkey,
                       float* __restrict__ partials) {
    int w = threadIdx.x >> 6, lane = threadIdx.x & 63;
    int row = blockIdx.x * 4 + w;
    ull pk = pkey[row], nk = nkey[row];
    float loss = 0.0f, wt = 0.0f;
    if (pk != 0ULL && nk != 0ULL) {
        int pi = (int)(0xFFFFFFFFu - (unsigned)(pk & 0xFFFFFFFFu));
        int ni = (int)(0xFFFFFFFFu - (unsigned)(nk & 0xFFFFFFFFu));
        float2 av = ((const float2*)(e + (size_t)row * DD))[lane];
        float2 pv = ((const float2*)(e + (size_t)pi * DD))[lane];
        float2 nv = ((const float2*)(e + (size_t)ni * DD))[lane];
        float dx, dy;
        dx = av.x - pv.x + EPSF; dy = av.y - pv.y + EPSF;
        float ap2 = dx * dx + dy * dy;
        dx = av.x - nv.x + EPSF; dy = av.y - nv.y + EPSF;
        float an2 = dx * dx + dy * dy;
        dx = pv.x - nv.x + EPSF; dy = pv.y - nv.y + EPSF;
        float pn2 = dx * dx + dy * dy;
        #pragma unroll
        for (int off = 32; off > 0; off >>= 1) {
            ap2 += __shfl_down(ap2, off);
            an2 += __shfl_down(an2, off);
            pn2 += __shfl_down(pn2, off);
        }
        if (lane == 0) {
            float ap = sqrtf(ap2), an = sqrtf(an2), pn = sqrtf(pn2);
            loss = fmaxf(ap - fminf(an, pn) + MARGINF, 0.0f);
            wt = 1.0f;
        }
    }
    __shared__ float sl[4], sw[4];
    if (lane == 0) { sl[w] = loss; sw[w] = wt; }
    __syncthreads();
    if (threadIdx.x == 0) {
        partials[blockIdx.x * 2 + 0] = sl[0] + sl[1] + sl[2] + sl[3];
        partials[blockIdx.x * 2 + 1] = sw[0] + sw[1] + sw[2] + sw[3];
    }
}

// --- finalize ---
__global__ void k_final(const float* __restrict__ partials, float* __restrict__ out) {
    int tid = threadIdx.x;
    float L = 0.0f, W = 0.0f;
    for (int i = 0; i < 4; i++) {
        int idx = tid + i * 256;
        L += partials[idx * 2];
        W += partials[idx * 2 + 1];
    }
    #pragma unroll
    for (int off = 32; off > 0; off >>= 1) {
        L += __shfl_down(L, off);
        W += __shfl_down(W, off);
    }
    __shared__ float sl[4], sw[4];
    int w = tid >> 6, lane = tid & 63;
    if (lane == 0) { sl[w] = L; sw[w] = W; }
    __syncthreads();
    if (tid == 0) {
        float Lt = sl[0] + sl[1] + sl[2] + sl[3];
        float Wt = sw[0] + sw[1] + sw[2] + sw[3];
        out[0] = Lt / fmaxf(Wt, 1.0f);
    }
}

extern "C" void kernel_launch(void* const* d_in, const int* in_sizes, int n_in,
                              void* d_out, int out_size, void* d_ws, size_t ws_size,
                              hipStream_t stream) {
    const float* e    = (const float*)d_in[0];
    const int*   tidx = (const int*)d_in[1];
    const int*   pos  = (const int*)d_in[2];
    const int*   neg  = (const int*)d_in[3];
    float* out = (float*)d_out;

    char* p = (char*)d_ws;
    ull* pkey  = (ull*)p;                 p += (size_t)BN * 8;      // 32 KB
    ull* nkey  = (ull*)p;                 p += (size_t)BN * 8;      // 32 KB
    float* rjp = (float*)p;               p += (size_t)BN * 4;      // 16 KB
    unsigned int* jn = (unsigned int*)p;  p += (size_t)BN * 4;      // 16 KB
    float* partials = (float*)p;          p += 2048 * 4;            // 8 KB
    unsigned int* ehi = (unsigned int*)p;   p += (size_t)BN * 64 * 4; // 1 MB
    unsigned int* eperm = (unsigned int*)p; p += (size_t)BN * 64 * 4; // 1 MB
    ull* pbits = (ull*)p;                 p += (size_t)BN * 64 * 8;  // 2 MB
    ull* nbits = (ull*)p;                 p += (size_t)BN * 64 * 8;  // 2 MB
    // ws budget ~6.2 MB: proven available in round 6 (bits path ran)

    k_prep<<<BN / 4, 256, 0, stream>>>(e, tidx, pos, neg, rjp, jn,
                                       pkey, nkey, ehi, eperm, pbits, nbits);
    dim3 grid(BN / 16, 4);
    k_select<<<grid, 256, 0, stream>>>((const ushort*)ehi, (const ushort*)eperm,
                                       pbits, nbits, rjp, jn, pkey, nkey);
    k_loss<<<BN / 4, 256, 0, stream>>>(e, pkey, nkey, partials);
    k_final<<<1, 256, 0, stream>>>(partials, out);
}

// Round 8
// 182.057 us; speedup vs baseline: 5.8359x; 1.0243x over previous
//
#include <hip/hip_runtime.h>
#include <stdint.h>

#define BN 4096
#define DD 128
#define EPSF 1e-6f
#define MARGINF 1.0f

typedef unsigned long long ull;
typedef unsigned short ushort;
typedef short short8 __attribute__((ext_vector_type(8)));
typedef float f32x4 __attribute__((ext_vector_type(4)));

__device__ __forceinline__ unsigned int ord_f32(float f) {
    unsigned int u = __float_as_uint(f);
    return (u & 0x80000000u) ? ~u : (u | 0x80000000u);
}
__device__ __forceinline__ ushort bf16_rne(float x) {
    unsigned int u = __float_as_uint(x);
    return (ushort)((u + 0x7FFFu + ((u >> 16) & 1u)) >> 16);
}

// --- prep + mask bit-compress (ballot path, proven R7) ---
// One wave per row; dword-per-lane coalesced mask loads, 32 outstanding
// (8 KB/wave in flight); __ballot(v!=0) IS the 64-col bit word.
__global__ __launch_bounds__(256)
void k_prep(const float* __restrict__ e, const int* __restrict__ tidx,
            const int* __restrict__ pos, const int* __restrict__ neg,
            float* __restrict__ rjp, unsigned int* __restrict__ jn,
            unsigned int* __restrict__ ehi, unsigned int* __restrict__ eperm,
            ull* __restrict__ pbits, ull* __restrict__ nbits) {
    const int w = threadIdx.x >> 6, lane = threadIdx.x & 63;
    const int row = blockIdx.x * 4 + w;
    const int c = tidx[row];                 // wave-uniform broadcast
    float2 v = ((const float2*)(e + (size_t)row * DD))[lane];
    ushort hx = bf16_rne(v.x), hy = bf16_rne(v.y);
    unsigned int packed = (unsigned int)hx | ((unsigned int)hy << 16);
    ehi[row * 64 + lane] = packed;
    eperm[(size_t)c * 64 + lane] = packed;   // permuted-column copy
    float ss = v.x + v.y;
    float qq = v.x * v.x + v.y * v.y;
    #pragma unroll
    for (int off = 32; off > 0; off >>= 1) {
        ss += __shfl_down(ss, off);
        qq += __shfl_down(qq, off);
    }
    if (lane == 0) {
        rjp[c] = qq - 2.0f * EPSF * ss;
        jn[c] = 0xFFFFFFFFu - (unsigned int)row;
    }

    // word m covers cols 64m..64m+63; bit l = col 64m+l
    const int* prow = pos + (size_t)row * BN;
    const int* nrow = neg + (size_t)row * BN;
    ull myp = 0ULL, myn = 0ULL;
    #pragma unroll
    for (int j0 = 0; j0 < 64; j0 += 16) {
        int pv[16], nv[16];
        #pragma unroll
        for (int k = 0; k < 16; k++)
            pv[k] = __builtin_nontemporal_load(prow + (j0 + k) * 64 + lane);
        #pragma unroll
        for (int k = 0; k < 16; k++)
            nv[k] = __builtin_nontemporal_load(nrow + (j0 + k) * 64 + lane);
        #pragma unroll
        for (int k = 0; k < 16; k++) {
            ull bp = __ballot(pv[k] != 0);
            ull bn = __ballot(nv[k] != 0);
            if (lane == j0 + k) { myp = bp; myn = bn; }
        }
    }
    pbits[(size_t)row * 64 + lane] = myp;    // coalesced 512 B/wave
    nbits[(size_t)row * 64 + lane] = myn;
}

// --- fused MFMA + selection + LOSS; block = 16 rows x ALL 4096 cols ---
// 512 threads (8 waves), grid 256. Because the block sees every column,
// per-row keys are block-complete: no pkey/nkey global round-trip, no
// atomicMax, no separate k_loss launch. Bit tile (16 KB) + rj/jn (32 KB)
// staged in LDS; only in-loop global stream is L2-hot eperm fragments.
__global__ __launch_bounds__(512, 4)
void k_sel_loss(const float* __restrict__ e,
                const ushort* __restrict__ ehi, const ushort* __restrict__ eperm,
                const ull* __restrict__ pbits, const ull* __restrict__ nbits,
                const float* __restrict__ rjp, const unsigned int* __restrict__ jn,
                float* __restrict__ partials) {
    __shared__ float rjL[4096];
    __shared__ unsigned int jnL[4096];
    __shared__ ull bitP[16 * 65], bitN[16 * 65];   // [16 rows][65] (pad kills bank conflict)
    __shared__ ull scrp[16 * 8], scrn[16 * 8];     // [row][wave]
    __shared__ ull fkp[16], fkn[16];
    __shared__ float lossL[16], wtL[16];

    const int tid = threadIdx.x;
    const int lane = tid & 63, w = tid >> 6;       // w in [0,8)
    const int lrow = lane & 15, quad = lane >> 4;
    const int r0 = blockIdx.x * 16;
    const int wof = w >> 2;                        // which 64-col word within 128
    const int shft = (w & 3) * 16 + lrow;          // bit within that word

    #pragma unroll
    for (int k = 0; k < 8; k++) {
        int idx = k * 512 + tid;
        rjL[idx] = rjp[idx];
        jnL[idx] = jn[idx];
    }
    #pragma unroll
    for (int k = 0; k < 2; k++) {
        int idx = k * 512 + tid;                   // [0,1024): row=idx>>6, word=idx&63
        bitP[(idx >> 6) * 65 + (idx & 63)] = pbits[(size_t)(r0 + (idx >> 6)) * 64 + (idx & 63)];
        bitN[(idx >> 6) * 65 + (idx & 63)] = nbits[(size_t)(r0 + (idx >> 6)) * 64 + (idx & 63)];
    }

    // A fragments: 16 rows, loaded once, reused for all 32 column tiles
    short8 a[4];
    #pragma unroll
    for (int ks = 0; ks < 4; ks++)
        a[ks] = *(const short8*)(ehi + (size_t)(r0 + lrow) * DD + ks * 32 + quad * 8);

    __syncthreads();

    ull kp[4] = {0ULL, 0ULL, 0ULL, 0ULL};
    ull kn[4] = {0ULL, 0ULL, 0ULL, 0ULL};

    short8 bf[2][4];
    float rjc[2]; unsigned int jni[2];

#define LOADTILE(BUF, JT) do {                                                  \
        const int lcol = (JT) * 128 + w * 16 + lrow;                            \
        rjc[BUF] = rjL[lcol];                                                   \
        jni[BUF] = jnL[lcol];                                                   \
        const ushort* bp = eperm + (size_t)lcol * DD + quad * 8;                \
        _Pragma("unroll")                                                       \
        for (int ks = 0; ks < 4; ks++)                                          \
            bf[BUF][ks] = *(const short8*)(bp + ks * 32);                       \
    } while (0)

#define COMPUTE(BUF, JT) do {                                                   \
        f32x4 acc = (f32x4){0.f, 0.f, 0.f, 0.f};                                \
        _Pragma("unroll")                                                       \
        for (int ks = 0; ks < 4; ks++)                                          \
            acc = __builtin_amdgcn_mfma_f32_16x16x32_bf16(a[ks], bf[BUF][ks], acc, 0, 0, 0); \
        _Pragma("unroll")                                                       \
        for (int t = 0; t < 4; t++) {                                           \
            ull pw = bitP[(quad * 4 + t) * 65 + 2 * (JT) + wof];                \
            ull nw = bitN[(quad * 4 + t) * 65 + 2 * (JT) + wof];                \
            float m = rjc[BUF] - 2.0f * acc[t];                                 \
            unsigned int om = ord_f32(m);                                       \
            ull keyp = ((ull)om << 32) | (ull)jni[BUF];                         \
            ull keyn = ((ull)(om ^ 0xFFFFFFFFu) << 32) | (ull)jni[BUF];         \
            if (((pw >> shft) & 1ULL) && keyp > kp[t]) kp[t] = keyp;            \
            if (((nw >> shft) & 1ULL) && keyn > kn[t]) kn[t] = keyn;            \
        }                                                                       \
    } while (0)

    LOADTILE(0, 0);
    for (int jt2 = 0; jt2 < 16; jt2++) {           // 32 tiles, 2 per iter (static buf idx)
        const int jA = 2 * jt2, jB = 2 * jt2 + 1;
        LOADTILE(1, jB);
        COMPUTE(0, jA);
        if (jt2 < 15) LOADTILE(0, jB + 1);
        COMPUTE(1, jB);
    }
#undef LOADTILE
#undef COMPUTE

    // fold across the 16 lanes of each quad (same rows, different cols)
    #pragma unroll
    for (int t = 0; t < 4; t++) {
        #pragma unroll
        for (int off = 8; off > 0; off >>= 1) {
            ull o = __shfl_xor(kp[t], off); if (o > kp[t]) kp[t] = o;
            o = __shfl_xor(kn[t], off);     if (o > kn[t]) kn[t] = o;
        }
        if (lrow == 0) {
            scrp[(quad * 4 + t) * 8 + w] = kp[t];
            scrn[(quad * 4 + t) * 8 + w] = kn[t];
        }
    }
    __syncthreads();
    if (tid < 16) {
        ull xp = 0ULL, xn = 0ULL;
        #pragma unroll
        for (int k = 0; k < 8; k++) {
            ull v = scrp[tid * 8 + k]; if (v > xp) xp = v;
            v = scrn[tid * 8 + k];     if (v > xn) xn = v;
        }
        fkp[tid] = xp; fkn[tid] = xn;
    }
    __syncthreads();

    // loss: wave w handles rows 2w, 2w+1 (keys are block-complete)
    #pragma unroll
    for (int rr = 0; rr < 2; rr++) {
        const int r16 = w * 2 + rr;
        const int row = r0 + r16;
        ull pk = fkp[r16], nk = fkn[r16];
        float loss = 0.0f, wt = 0.0f;
        if (pk != 0ULL && nk != 0ULL) {
            int pi = (int)(0xFFFFFFFFu - (unsigned)(pk & 0xFFFFFFFFu));
            int ni = (int)(0xFFFFFFFFu - (unsigned)(nk & 0xFFFFFFFFu));
            float2 av = ((const float2*)(e + (size_t)row * DD))[lane];
            float2 pv = ((const float2*)(e + (size_t)pi * DD))[lane];
            float2 nv = ((const float2*)(e + (size_t)ni * DD))[lane];
            float dx, dy;
            dx = av.x - pv.x + EPSF; dy = av.y - pv.y + EPSF;
            float ap2 = dx * dx + dy * dy;
            dx = av.x - nv.x + EPSF; dy = av.y - nv.y + EPSF;
            float an2 = dx * dx + dy * dy;
            dx = pv.x - nv.x + EPSF; dy = pv.y - nv.y + EPSF;
            float pn2 = dx * dx + dy * dy;
            #pragma unroll
            for (int off = 32; off > 0; off >>= 1) {
                ap2 += __shfl_down(ap2, off);
                an2 += __shfl_down(an2, off);
                pn2 += __shfl_down(pn2, off);
            }
            if (lane == 0) {
                float ap = sqrtf(ap2), an = sqrtf(an2), pn = sqrtf(pn2);
                loss = fmaxf(ap - fminf(an, pn) + MARGINF, 0.0f);
                wt = 1.0f;
            }
        }
        if (lane == 0) { lossL[r16] = loss; wtL[r16] = wt; }
    }
    __syncthreads();
    if (tid == 0) {
        float L = 0.0f, W = 0.0f;
        #pragma unroll
        for (int k = 0; k < 16; k++) { L += lossL[k]; W += wtL[k]; }
        partials[blockIdx.x * 2 + 0] = L;
        partials[blockIdx.x * 2 + 1] = W;
    }
}

// --- finalize: 256 block-partials, fixed order ---
__global__ void k_final(const float* __restrict__ partials, float* __restrict__ out) {
    int tid = threadIdx.x;
    float L = partials[tid * 2], W = partials[tid * 2 + 1];
    #pragma unroll
    for (int off = 32; off > 0; off >>= 1) {
        L += __shfl_down(L, off);
        W += __shfl_down(W, off);
    }
    __shared__ float sl[4], sw[4];
    int w = tid >> 6, lane = tid & 63;
    if (lane == 0) { sl[w] = L; sw[w] = W; }
    __syncthreads();
    if (tid == 0) {
        float Lt = sl[0] + sl[1] + sl[2] + sl[3];
        float Wt = sw[0] + sw[1] + sw[2] + sw[3];
        out[0] = Lt / fmaxf(Wt, 1.0f);
    }
}

extern "C" void kernel_launch(void* const* d_in, const int* in_sizes, int n_in,
                              void* d_out, int out_size, void* d_ws, size_t ws_size,
                              hipStream_t stream) {
    const float* e    = (const float*)d_in[0];
    const int*   tidx = (const int*)d_in[1];
    const int*   pos  = (const int*)d_in[2];
    const int*   neg  = (const int*)d_in[3];
    float* out = (float*)d_out;

    char* p = (char*)d_ws;
    float* rjp = (float*)p;               p += (size_t)BN * 4;       // 16 KB
    unsigned int* jn = (unsigned int*)p;  p += (size_t)BN * 4;       // 16 KB
    float* partials = (float*)p;          p += 512 * 4;              // 2 KB
    unsigned int* ehi = (unsigned int*)p;   p += (size_t)BN * 64 * 4; // 1 MB
    unsigned int* eperm = (unsigned int*)p; p += (size_t)BN * 64 * 4; // 1 MB
    ull* pbits = (ull*)p;                 p += (size_t)BN * 64 * 8;   // 2 MB
    ull* nbits = (ull*)p;                 p += (size_t)BN * 64 * 8;   // 2 MB
    // total ~6.1 MB: proven available (bits path ran in R6/R7)

    k_prep<<<BN / 4, 256, 0, stream>>>(e, tidx, pos, neg, rjp, jn,
                                       ehi, eperm, pbits, nbits);
    k_sel_loss<<<BN / 16, 512, 0, stream>>>(e, (const ushort*)ehi, (const ushort*)eperm,
                                            pbits, nbits, rjp, jn, partials);
    k_final<<<1, 256, 0, stream>>>(partials, out);
}